// Round 4
// baseline (428.500 us; speedup 1.0000x reference)
//
#include <hip/hip_runtime.h>
#include <hip/hip_bf16.h>

// ---------- types ----------
typedef __bf16 bf16x8 __attribute__((ext_vector_type(8)));
typedef __bf16 bf16x4 __attribute__((ext_vector_type(4)));
typedef float  f32x4  __attribute__((ext_vector_type(4)));

typedef const __attribute__((address_space(1))) void* gptr_t;
typedef __attribute__((address_space(3))) void*       lptr_t;

#define NQ 2048
#define NK 2048
#define AD 1024
#define NH 16
#define HD 64
#define HC 1024   // NH*HD

// ---------- fused prep: convert q/m to bf16 (blocks 0..4095) +
//            transpose 4 weights fp32[a][hc] -> bf16[hc][a] (blocks 4096..5119)
// Write phase vectorized (bisect round: this is the ONLY change vs the
// round-2 known-good kernel): each lane gathers 8 consecutive-a elements
// from the LDS tile and stores one bf16x8 (16 B/lane). Provable from spec:
// o[j] = tile[g*8+j][nl] = W[a0+g*8+j][n0+nl], stored at T[n0+nl][a0+g*8+j];
// (nl,g) over 512 units covers the 64x64 tile bijectively.
__global__ __launch_bounds__(256) void prep_fused(
    const float* __restrict__ q_data, const float* __restrict__ m_data,
    __bf16* __restrict__ aq, __bf16* __restrict__ am,
    const float* __restrict__ w0, const float* __restrict__ w1,
    const float* __restrict__ w2, const float* __restrict__ w3,
    __bf16* __restrict__ t0, __bf16* __restrict__ t1,
    __bf16* __restrict__ t2, __bf16* __restrict__ t3) {
  __shared__ float tile[64][65];
  if (blockIdx.x < 4096) {
    const int NEL4 = NQ * AD / 4;
    int gid = blockIdx.x * 256 + threadIdx.x;
    float4 v;
    __bf16* dst;
    if (gid < NEL4) { v = ((const float4*)q_data)[gid]; dst = aq + (size_t)gid * 4; }
    else            { v = ((const float4*)m_data)[gid - NEL4]; dst = am + (size_t)(gid - NEL4) * 4; }
    bf16x4 o;
    o[0] = (__bf16)v.x; o[1] = (__bf16)v.y; o[2] = (__bf16)v.z; o[3] = (__bf16)v.w;
    *(bf16x4*)dst = o;
    return;
  }
  int b = blockIdx.x - 4096;
  int wsel = b >> 8;
  int t = b & 255;
  int a0 = (t >> 4) * 64, n0 = (t & 15) * 64;
  const float* W = (wsel == 0) ? w0 : (wsel == 1) ? w1 : (wsel == 2) ? w2 : w3;
  __bf16*      T = (wsel == 0) ? t0 : (wsel == 1) ? t1 : (wsel == 2) ? t2 : t3;
  int tx = threadIdx.x & 63, ty = threadIdx.x >> 6;
#pragma unroll
  for (int r = 0; r < 64; r += 4)
    tile[ty + r][tx] = W[(size_t)(a0 + ty + r) * HC + n0 + tx];
  __syncthreads();
#pragma unroll
  for (int e = 0; e < 2; e++) {
    int unit = threadIdx.x + e * 256;
    int nl = unit >> 3, g = unit & 7;   // nl: hc-row 0..63, g: a-group 0..7
    bf16x8 o;
#pragma unroll
    for (int j = 0; j < 8; j++) o[j] = (__bf16)tile[g * 8 + j][nl];
    *(bf16x8*)(T + (size_t)(n0 + nl) * AD + a0 + g * 8) = o;
  }
}

// ---------- projection GEMM v3 (round-2 exact, known-good) ----------
// BK=64, double-buffered, 16 barriers total. LDS 64 KB. Swizzled staging
// (slot = chunk ^ (row&7), linear LDS dest) + same XOR on fragment reads.
// XCD-chunked block swizzle (bijective, 512 % 8 == 0).
// Epilogue: scalar stores (round-3's LDS-staged epilogue failed correctness;
// reverted for bisect — retry simplified next round if this passes).
__global__ __launch_bounds__(256) void proj_gemm(
    const __bf16* __restrict__ Aq, const __bf16* __restrict__ Am,
    const __bf16* __restrict__ Wq, const __bf16* __restrict__ Wk,
    const __bf16* __restrict__ Wv, const __bf16* __restrict__ Wg,
    const float* __restrict__ qbias,
    __bf16* __restrict__ qbf, __bf16* __restrict__ kb,
    __bf16* __restrict__ vt, float* __restrict__ gate) {
  __shared__ __bf16 As[2][128 * 64];
  __shared__ __bf16 Bs[2][128 * 64];
  int bx0 = blockIdx.x;
  int bx = (bx0 & 7) * 64 + (bx0 >> 3);   // bijective: 512 % 8 == 0
  int mode = bx >> 7, t = bx & 127;
  const __bf16 *A, *B;
  int bm, bn;
  if (mode == 2) {
    A = Wv; B = Am; bm = (t >> 4) << 7; bn = (t & 15) << 7;
  } else {
    bm = (t >> 3) << 7; bn = (t & 7) << 7;
    A = (mode == 1) ? Am : Aq;
    B = (mode == 0) ? Wq : (mode == 1) ? Wk : Wg;
  }
  int lane = threadIdx.x & 63, wave = threadIdx.x >> 6;
  int quad = lane >> 4, l15 = lane & 15;
  int wm = (wave >> 1) << 6, wn = (wave & 1) << 6;
  int srow = lane >> 3, schunk = lane & 7;   // 8 rows x 8 chunks per instr

  f32x4 acc[4][4] = {};

#define PSTAGE(bufi, k0s)                                                     \
  {                                                                           \
    _Pragma("unroll")                                                         \
    for (int j = 0; j < 4; j++) {                                             \
      int inst = wave * 4 + j;                                                \
      int row = inst * 8 + srow;                                              \
      int sc = schunk ^ (row & 7);                                            \
      __builtin_amdgcn_global_load_lds(                                       \
          (gptr_t)((const char*)A + ((size_t)(bm + row) * AD + (k0s)) * 2 + sc * 16), \
          (lptr_t)(&As[bufi][inst * 512]), 16, 0, 0);                         \
      __builtin_amdgcn_global_load_lds(                                       \
          (gptr_t)((const char*)B + ((size_t)(bn + row) * AD + (k0s)) * 2 + sc * 16), \
          (lptr_t)(&Bs[bufi][inst * 512]), 16, 0, 0);                         \
    }                                                                         \
  }

  PSTAGE(0, 0)

  for (int kt = 0; kt < 16; ++kt) {
    int buf = kt & 1;
    __syncthreads();  // stage(kt) landed; buf^1 ds_reads from kt-1 done
    if (kt < 15) PSTAGE(buf ^ 1, (kt + 1) * 64)

#pragma unroll
    for (int kk = 0; kk < 2; kk++) {
      bf16x8 af[4], bfr[4];
#pragma unroll
      for (int i = 0; i < 4; i++) {
        int R = wm + i * 16 + l15;
        int slot = (kk * 4 + quad) ^ (l15 & 7);
        af[i] = *(const bf16x8*)(&As[buf][R * 64 + slot * 8]);
      }
#pragma unroll
      for (int j = 0; j < 4; j++) {
        int R = wn + j * 16 + l15;
        int slot = (kk * 4 + quad) ^ (l15 & 7);
        bfr[j] = *(const bf16x8*)(&Bs[buf][R * 64 + slot * 8]);
      }
      __builtin_amdgcn_s_setprio(1);
#pragma unroll
      for (int i = 0; i < 4; i++)
#pragma unroll
        for (int j = 0; j < 4; j++)
          acc[i][j] = __builtin_amdgcn_mfma_f32_16x16x32_bf16(af[i], bfr[j], acc[i][j], 0, 0, 0);
      __builtin_amdgcn_s_setprio(0);
    }
  }

#pragma unroll
  for (int j = 0; j < 4; j++) {
    int n = bn + wn + j * 16 + l15;
    float qbb = (mode == 0) ? qbias[n] : 0.f;
#pragma unroll
    for (int i = 0; i < 4; i++) {
#pragma unroll
      for (int r = 0; r < 4; r++) {
        int m = bm + wm + i * 16 + quad * 4 + r;
        float v = acc[i][j][r];
        if (mode == 0) {
          int h = n >> 6, c = n & 63;
          qbf[((size_t)h * NQ + m) * HD + c] = (__bf16)((v + qbb) * 0.125f);
        } else if (mode == 1) {
          int h = n >> 6, c = n & 63;
          kb[((size_t)h * NK + m) * HD + c] = (__bf16)v;
        } else if (mode == 2) {
          vt[(size_t)m * NK + n] = (__bf16)v;
        } else {
          gate[(size_t)m * HC + n] = 1.f / (1.f + __expf(-v));
        }
      }
    }
  }
}

// ---------- flash attention v4 (+ setprio around MFMA clusters) ----------
// block = (head, 64 q rows), 4 waves sharing LDS K/V 128-k tiles (2 subs of
// 64), double-buffered global_load_lds. Permuted B-fragments: fragment jt
// holds k-row 4*l15+jt so (a) bias tiles load as coalesced float4/lane,
// (b) P-stores are ds_write_b64, (c) P lands in plain [q][k] LDS layout.
// 16 barriers total; prefetch slack = 1 full 128-k tile (> HBM latency).
// BW-bound on the 268 MB fp32 bias stream (read exactly once); K/V per head
// = 512 KB, L2-served (all 32 blocks of head h land on XCD h%8).
__global__ __launch_bounds__(256, 2) void attn(
    const __bf16* __restrict__ qbuf, const __bf16* __restrict__ kbuf,
    const __bf16* __restrict__ vtb, const float* __restrict__ gate,
    const float* __restrict__ bias, float* __restrict__ out) {
  __shared__ __bf16 Kt[2][128 * 64];     // [k-row][d], swizzle f=(row>>2)&7
  __shared__ __bf16 Vt[2][64 * 128];     // [d-row][k], swizzle f=row&15
  __shared__ __bf16 P_lds[4][16 * 68];   // per-wave P buffer, [q][k] layout

  int bx = blockIdx.x;
  int h = bx & 15, qb0 = bx >> 4;
  int lane = threadIdx.x & 63, wave = threadIdx.x >> 6;
  int quad = lane >> 4, l15 = lane & 15;
  int qrow = (qb0 << 6) + wave * 16;

  const __bf16* qh = qbuf + (size_t)h * NQ * HD;
  const __bf16* kh = kbuf + (size_t)h * NK * HD;
  const __bf16* vh = vtb + (size_t)h * HD * NK;
  const float*  bh = bias + (size_t)h * NQ * NK;

  bf16x8 a_q[2];
#pragma unroll
  for (int kk = 0; kk < 2; kk++)
    a_q[kk] = *(const bf16x8*)(qh + (size_t)(qrow + l15) * HD + quad * 8 + kk * 32);

  float lpart[4] = {0.f, 0.f, 0.f, 0.f};
  f32x4 acc_o[4] = {};
  __bf16* pl = &P_lds[wave][0];

  // ---- staging helper: 16 K-instrs + 16 V-instrs per tile, 4+4 per wave ----
  int srowK = lane >> 3;                 // 0..7
  int srowV = lane >> 4;                 // 0..3
#define STAGE(bufi, k0s)                                                      \
  {                                                                           \
    _Pragma("unroll")                                                         \
    for (int j = 0; j < 4; j++) {                                             \
      int i = wave * 4 + j;                                                   \
      int rK = i * 8 + srowK;                                                 \
      int cK = (lane & 7) ^ ((2 * i + (srowK >> 2)) & 7);                     \
      __builtin_amdgcn_global_load_lds(                                       \
          (gptr_t)(kh + (size_t)(k0s + rK) * 64 + cK * 8),                    \
          (lptr_t)(&Kt[bufi][i * 512]), 16, 0, 0);                            \
      int rV = i * 4 + srowV;                                                 \
      int cV = (lane & 15) ^ ((i * 4 + srowV) & 15);                          \
      __builtin_amdgcn_global_load_lds(                                       \
          (gptr_t)(vh + (size_t)rV * NK + k0s + cV * 8),                      \
          (lptr_t)(&Vt[bufi][i * 512]), 16, 0, 0);                            \
    }                                                                         \
  }

  STAGE(0, 0)

  // bias prefetch tile 0: per lane float4 at k = 4*l15 (+64 for sub1)
  f32x4 spc[8];  // [sub*4 + r]
#pragma unroll
  for (int s = 0; s < 2; s++)
#pragma unroll
    for (int r = 0; r < 4; r++)
      spc[s * 4 + r] = *(const f32x4*)(bh + (size_t)(qrow + quad * 4 + r) * NK + s * 64 + 4 * l15);

  for (int t = 0; t < 16; ++t) {
    int buf = t & 1;
    __syncthreads();  // stage(t) + bias(t) landed; buf^1 reads done

    if (t < 15) STAGE(buf ^ 1, (t + 1) * 128)

    // move bias into S accumulators, then start prefetching tile t+1
    f32x4 s2[2][4];
#pragma unroll
    for (int s = 0; s < 2; s++)
#pragma unroll
      for (int jt = 0; jt < 4; jt++)
#pragma unroll
        for (int r = 0; r < 4; r++)
          s2[s][jt][r] = spc[s * 4 + r][jt];

    if (t < 15) {
      const float* bn_ = bh + (size_t)(t + 1) * 128;
#pragma unroll
      for (int s = 0; s < 2; s++)
#pragma unroll
        for (int r = 0; r < 4; r++)
          spc[s * 4 + r] = *(const f32x4*)(bn_ + (size_t)(qrow + quad * 4 + r) * NK + s * 64 + 4 * l15);
    }

    const __bf16* Kb = &Kt[buf][0];
    const __bf16* Vb = &Vt[buf][0];

#pragma unroll
    for (int s = 0; s < 2; s++) {
      // K fragments: permuted rows R = s*64 + 4*l15 + jt; f(R)= (R>>2)&7 = l15&7
      bf16x8 b_k[4][2];
#pragma unroll
      for (int jt = 0; jt < 4; jt++)
#pragma unroll
        for (int kk = 0; kk < 2; kk++) {
          int R = s * 64 + 4 * l15 + jt;
          int pc = (quad + 4 * kk) ^ (l15 & 7);
          b_k[jt][kk] = *(const bf16x8*)(Kb + R * 64 + pc * 8);
        }

      __builtin_amdgcn_s_setprio(1);
#pragma unroll
      for (int jt = 0; jt < 4; jt++)
#pragma unroll
        for (int kk = 0; kk < 2; kk++)
          s2[s][jt] = __builtin_amdgcn_mfma_f32_16x16x32_bf16(a_q[kk], b_k[jt][kk], s2[s][jt], 0, 0, 0);
      __builtin_amdgcn_s_setprio(0);

      // exp + P store: per r one ds_write_b64 of 4 bf16 (k = 4*l15 + jt)
#pragma unroll
      for (int r = 0; r < 4; r++) {
        bf16x4 w;
#pragma unroll
        for (int jt = 0; jt < 4; jt++) {
          float pv = __expf(s2[s][jt][r]);
          lpart[r] += pv;
          w[jt] = (__bf16)pv;
        }
        *(bf16x4*)(pl + (quad * 4 + r) * 68 + 4 * l15) = w;
      }

      // A-fragment of P: plain [q][k] read
      bf16x8 a_p[2];
#pragma unroll
      for (int kk = 0; kk < 2; kk++) {
        const __bf16* src = pl + l15 * 68 + quad * 8 + kk * 32;
        bf16x4 lo = *(const bf16x4*)src;
        bf16x4 hi = *(const bf16x4*)(src + 4);
        bf16x8 a;
#pragma unroll
        for (int j = 0; j < 4; j++) { a[j] = lo[j]; a[4 + j] = hi[j]; }
        a_p[kk] = a;
      }

      // V fragments: rows jt*16+l15, chunk (s*8+kk*4+quad) ^ l15
      bf16x8 b_v[4][2];
#pragma unroll
      for (int jt = 0; jt < 4; jt++)
#pragma unroll
        for (int kk = 0; kk < 2; kk++) {
          int R = jt * 16 + l15;
          int pc = (s * 8 + kk * 4 + quad) ^ l15;
          b_v[jt][kk] = *(const bf16x8*)(Vb + R * 128 + pc * 8);
        }

      __builtin_amdgcn_s_setprio(1);
#pragma unroll
      for (int jt = 0; jt < 4; jt++)
#pragma unroll
        for (int kk = 0; kk < 2; kk++)
          acc_o[jt] = __builtin_amdgcn_mfma_f32_16x16x32_bf16(a_p[kk], b_v[jt][kk], acc_o[jt], 0, 0, 0);
      __builtin_amdgcn_s_setprio(0);
    }
  }

  // epilogue: 16-lane row-sum reduce, gate, store
#pragma unroll
  for (int off = 1; off < 16; off <<= 1)
#pragma unroll
    for (int r = 0; r < 4; r++) lpart[r] += __shfl_xor(lpart[r], off);
  float inv[4];
#pragma unroll
  for (int r = 0; r < 4; r++) inv[r] = 1.f / lpart[r];
#pragma unroll
  for (int jt = 0; jt < 4; jt++)
#pragma unroll
    for (int r = 0; r < 4; r++) {
      int q = qrow + quad * 4 + r;
      int d = jt * 16 + l15;
      float g = gate[(size_t)q * HC + h * HD + d];
      out[((size_t)q * NH + h) * HD + d] = acc_o[jt][r] * inv[r] * g;
    }
}

// ---------- launch ----------
extern "C" void kernel_launch(void* const* d_in, const int* in_sizes, int n_in,
                              void* d_out, int out_size, void* d_ws, size_t ws_size,
                              hipStream_t stream) {
  const float* q_data   = (const float*)d_in[0];
  const float* m_data   = (const float*)d_in[1];
  const float* bias     = (const float*)d_in[2];
  const float* query_w  = (const float*)d_in[3];
  const float* query_b  = (const float*)d_in[4];
  const float* key_w    = (const float*)d_in[5];
  const float* value_w  = (const float*)d_in[6];
  const float* gating_w = (const float*)d_in[7];
  float* out = (float*)d_out;

  char* ws = (char*)d_ws;
  __bf16* Aq   = (__bf16*)(ws);
  __bf16* Am   = (__bf16*)(ws + ((size_t)4 << 20));
  __bf16* Wq   = (__bf16*)(ws + ((size_t)8 << 20));
  __bf16* Wk   = (__bf16*)(ws + ((size_t)10 << 20));
  __bf16* Wv   = (__bf16*)(ws + ((size_t)12 << 20));
  __bf16* Wg   = (__bf16*)(ws + ((size_t)14 << 20));
  __bf16* qbuf = (__bf16*)(ws + ((size_t)16 << 20));
  __bf16* kbuf = (__bf16*)(ws + ((size_t)20 << 20));
  __bf16* vtb  = (__bf16*)(ws + ((size_t)24 << 20));
  float*  gbuf = (float*)(ws + ((size_t)28 << 20));

  prep_fused<<<5120, 256, 0, stream>>>(q_data, m_data, Aq, Am,
                                       query_w, key_w, value_w, gating_w,
                                       Wq, Wk, Wv, Wg);
  proj_gemm<<<512, 256, 0, stream>>>(Aq, Am, Wq, Wk, Wv, Wg, query_b, qbuf, kbuf, vtb, gbuf);
  attn<<<512, 256, 0, stream>>>(qbuf, kbuf, vtb, gbuf, bias, out);
}

// Round 5
// 408.082 us; speedup vs baseline: 1.0500x; 1.0500x over previous
//
#include <hip/hip_runtime.h>
#include <hip/hip_bf16.h>

// ---------- types ----------
typedef __bf16 bf16x8 __attribute__((ext_vector_type(8)));
typedef __bf16 bf16x4 __attribute__((ext_vector_type(4)));
typedef float  f32x4  __attribute__((ext_vector_type(4)));

typedef const __attribute__((address_space(1))) void* gptr_t;
typedef __attribute__((address_space(3))) void*       lptr_t;

#define NQ 2048
#define NK 2048
#define AD 1024
#define NH 16
#define HD 64
#define HC 1024   // NH*HD

// ---------- fused prep: convert q/m to bf16 (blocks 0..4095) +
//            transpose 4 weights fp32[a][hc] -> bf16[hc][a] (blocks 4096..5119)
// Write phase vectorized: each lane gathers 8 consecutive-a elements from
// the LDS tile and stores one bf16x8 (16 B/lane). Verified round 4.
__global__ __launch_bounds__(256) void prep_fused(
    const float* __restrict__ q_data, const float* __restrict__ m_data,
    __bf16* __restrict__ aq, __bf16* __restrict__ am,
    const float* __restrict__ w0, const float* __restrict__ w1,
    const float* __restrict__ w2, const float* __restrict__ w3,
    __bf16* __restrict__ t0, __bf16* __restrict__ t1,
    __bf16* __restrict__ t2, __bf16* __restrict__ t3) {
  __shared__ float tile[64][65];
  if (blockIdx.x < 4096) {
    const int NEL4 = NQ * AD / 4;
    int gid = blockIdx.x * 256 + threadIdx.x;
    float4 v;
    __bf16* dst;
    if (gid < NEL4) { v = ((const float4*)q_data)[gid]; dst = aq + (size_t)gid * 4; }
    else            { v = ((const float4*)m_data)[gid - NEL4]; dst = am + (size_t)(gid - NEL4) * 4; }
    bf16x4 o;
    o[0] = (__bf16)v.x; o[1] = (__bf16)v.y; o[2] = (__bf16)v.z; o[3] = (__bf16)v.w;
    *(bf16x4*)dst = o;
    return;
  }
  int b = blockIdx.x - 4096;
  int wsel = b >> 8;
  int t = b & 255;
  int a0 = (t >> 4) * 64, n0 = (t & 15) * 64;
  const float* W = (wsel == 0) ? w0 : (wsel == 1) ? w1 : (wsel == 2) ? w2 : w3;
  __bf16*      T = (wsel == 0) ? t0 : (wsel == 1) ? t1 : (wsel == 2) ? t2 : t3;
  int tx = threadIdx.x & 63, ty = threadIdx.x >> 6;
#pragma unroll
  for (int r = 0; r < 64; r += 4)
    tile[ty + r][tx] = W[(size_t)(a0 + ty + r) * HC + n0 + tx];
  __syncthreads();
#pragma unroll
  for (int e = 0; e < 2; e++) {
    int unit = threadIdx.x + e * 256;
    int nl = unit >> 3, g = unit & 7;   // nl: hc-row 0..63, g: a-group 0..7
    bf16x8 o;
#pragma unroll
    for (int j = 0; j < 8; j++) o[j] = (__bf16)tile[g * 8 + j][nl];
    *(bf16x8*)(T + (size_t)(n0 + nl) * AD + a0 + g * 8) = o;
  }
}

// ---------- projection GEMM v3 (round-2 exact, known-good) ----------
// BK=64, double-buffered, 16 barriers total. LDS 64 KB. Swizzled staging
// (slot = chunk ^ (row&7), linear LDS dest) + same XOR on fragment reads.
// XCD-chunked block swizzle (bijective, 512 % 8 == 0).
__global__ __launch_bounds__(256) void proj_gemm(
    const __bf16* __restrict__ Aq, const __bf16* __restrict__ Am,
    const __bf16* __restrict__ Wq, const __bf16* __restrict__ Wk,
    const __bf16* __restrict__ Wv, const __bf16* __restrict__ Wg,
    const float* __restrict__ qbias,
    __bf16* __restrict__ qbf, __bf16* __restrict__ kb,
    __bf16* __restrict__ vt, float* __restrict__ gate) {
  __shared__ __bf16 As[2][128 * 64];
  __shared__ __bf16 Bs[2][128 * 64];
  int bx0 = blockIdx.x;
  int bx = (bx0 & 7) * 64 + (bx0 >> 3);   // bijective: 512 % 8 == 0
  int mode = bx >> 7, t = bx & 127;
  const __bf16 *A, *B;
  int bm, bn;
  if (mode == 2) {
    A = Wv; B = Am; bm = (t >> 4) << 7; bn = (t & 15) << 7;
  } else {
    bm = (t >> 3) << 7; bn = (t & 7) << 7;
    A = (mode == 1) ? Am : Aq;
    B = (mode == 0) ? Wq : (mode == 1) ? Wk : Wg;
  }
  int lane = threadIdx.x & 63, wave = threadIdx.x >> 6;
  int quad = lane >> 4, l15 = lane & 15;
  int wm = (wave >> 1) << 6, wn = (wave & 1) << 6;
  int srow = lane >> 3, schunk = lane & 7;   // 8 rows x 8 chunks per instr

  f32x4 acc[4][4] = {};

#define PSTAGE(bufi, k0s)                                                     \
  {                                                                           \
    _Pragma("unroll")                                                         \
    for (int j = 0; j < 4; j++) {                                             \
      int inst = wave * 4 + j;                                                \
      int row = inst * 8 + srow;                                              \
      int sc = schunk ^ (row & 7);                                            \
      __builtin_amdgcn_global_load_lds(                                       \
          (gptr_t)((const char*)A + ((size_t)(bm + row) * AD + (k0s)) * 2 + sc * 16), \
          (lptr_t)(&As[bufi][inst * 512]), 16, 0, 0);                         \
      __builtin_amdgcn_global_load_lds(                                       \
          (gptr_t)((const char*)B + ((size_t)(bn + row) * AD + (k0s)) * 2 + sc * 16), \
          (lptr_t)(&Bs[bufi][inst * 512]), 16, 0, 0);                         \
    }                                                                         \
  }

  PSTAGE(0, 0)

  for (int kt = 0; kt < 16; ++kt) {
    int buf = kt & 1;
    __syncthreads();  // stage(kt) landed; buf^1 ds_reads from kt-1 done
    if (kt < 15) PSTAGE(buf ^ 1, (kt + 1) * 64)

#pragma unroll
    for (int kk = 0; kk < 2; kk++) {
      bf16x8 af[4], bfr[4];
#pragma unroll
      for (int i = 0; i < 4; i++) {
        int R = wm + i * 16 + l15;
        int slot = (kk * 4 + quad) ^ (l15 & 7);
        af[i] = *(const bf16x8*)(&As[buf][R * 64 + slot * 8]);
      }
#pragma unroll
      for (int j = 0; j < 4; j++) {
        int R = wn + j * 16 + l15;
        int slot = (kk * 4 + quad) ^ (l15 & 7);
        bfr[j] = *(const bf16x8*)(&Bs[buf][R * 64 + slot * 8]);
      }
      __builtin_amdgcn_s_setprio(1);
#pragma unroll
      for (int i = 0; i < 4; i++)
#pragma unroll
        for (int j = 0; j < 4; j++)
          acc[i][j] = __builtin_amdgcn_mfma_f32_16x16x32_bf16(af[i], bfr[j], acc[i][j], 0, 0, 0);
      __builtin_amdgcn_s_setprio(0);
    }
  }

#pragma unroll
  for (int j = 0; j < 4; j++) {
    int n = bn + wn + j * 16 + l15;
    float qbb = (mode == 0) ? qbias[n] : 0.f;
#pragma unroll
    for (int i = 0; i < 4; i++) {
#pragma unroll
      for (int r = 0; r < 4; r++) {
        int m = bm + wm + i * 16 + quad * 4 + r;
        float v = acc[i][j][r];
        if (mode == 0) {
          int h = n >> 6, c = n & 63;
          qbf[((size_t)h * NQ + m) * HD + c] = (__bf16)((v + qbb) * 0.125f);
        } else if (mode == 1) {
          int h = n >> 6, c = n & 63;
          kb[((size_t)h * NK + m) * HD + c] = (__bf16)v;
        } else if (mode == 2) {
          vt[(size_t)m * NK + n] = (__bf16)v;
        } else {
          gate[(size_t)m * HC + n] = 1.f / (1.f + __expf(-v));
        }
      }
    }
  }
}

// ---------- flash attention v5: non-temporal bias stream ----------
// THE CHANGE (round 5, single-lever A/B vs round 4): bias is 268 MB of
// read-once fp32 — streaming it through L2 with normal loads evicts the
// K/V working set (2 heads x 1 MB per XCD) that the staging loop assumes
// is L2-resident, forcing K/V re-fetch from HBM (up to ~260 MB extra).
// __builtin_nontemporal_load emits the nt cache hint so bias doesn't
// claim L2 lines; K/V staging (global_load_lds, aux=0) caches normally.
__global__ __launch_bounds__(256, 2) void attn(
    const __bf16* __restrict__ qbuf, const __bf16* __restrict__ kbuf,
    const __bf16* __restrict__ vtb, const float* __restrict__ gate,
    const float* __restrict__ bias, float* __restrict__ out) {
  __shared__ __bf16 Kt[2][128 * 64];     // [k-row][d], swizzle f=(row>>2)&7
  __shared__ __bf16 Vt[2][64 * 128];     // [d-row][k], swizzle f=row&15
  __shared__ __bf16 P_lds[4][16 * 68];   // per-wave P buffer, [q][k] layout

  int bx = blockIdx.x;
  int h = bx & 15, qb0 = bx >> 4;
  int lane = threadIdx.x & 63, wave = threadIdx.x >> 6;
  int quad = lane >> 4, l15 = lane & 15;
  int qrow = (qb0 << 6) + wave * 16;

  const __bf16* qh = qbuf + (size_t)h * NQ * HD;
  const __bf16* kh = kbuf + (size_t)h * NK * HD;
  const __bf16* vh = vtb + (size_t)h * HD * NK;
  const float*  bh = bias + (size_t)h * NQ * NK;

  bf16x8 a_q[2];
#pragma unroll
  for (int kk = 0; kk < 2; kk++)
    a_q[kk] = *(const bf16x8*)(qh + (size_t)(qrow + l15) * HD + quad * 8 + kk * 32);

  float lpart[4] = {0.f, 0.f, 0.f, 0.f};
  f32x4 acc_o[4] = {};
  __bf16* pl = &P_lds[wave][0];

  // ---- staging helper: 16 K-instrs + 16 V-instrs per tile, 4+4 per wave ----
  int srowK = lane >> 3;                 // 0..7
  int srowV = lane >> 4;                 // 0..3
#define STAGE(bufi, k0s)                                                      \
  {                                                                           \
    _Pragma("unroll")                                                         \
    for (int j = 0; j < 4; j++) {                                             \
      int i = wave * 4 + j;                                                   \
      int rK = i * 8 + srowK;                                                 \
      int cK = (lane & 7) ^ ((2 * i + (srowK >> 2)) & 7);                     \
      __builtin_amdgcn_global_load_lds(                                       \
          (gptr_t)(kh + (size_t)(k0s + rK) * 64 + cK * 8),                    \
          (lptr_t)(&Kt[bufi][i * 512]), 16, 0, 0);                            \
      int rV = i * 4 + srowV;                                                 \
      int cV = (lane & 15) ^ ((i * 4 + srowV) & 15);                          \
      __builtin_amdgcn_global_load_lds(                                       \
          (gptr_t)(vh + (size_t)rV * NK + k0s + cV * 8),                      \
          (lptr_t)(&Vt[bufi][i * 512]), 16, 0, 0);                            \
    }                                                                         \
  }

  STAGE(0, 0)

  // bias prefetch tile 0: per lane float4 at k = 4*l15 (+64 for sub1), nt
  f32x4 spc[8];  // [sub*4 + r]
#pragma unroll
  for (int s = 0; s < 2; s++)
#pragma unroll
    for (int r = 0; r < 4; r++)
      spc[s * 4 + r] = __builtin_nontemporal_load(
          (const f32x4*)(bh + (size_t)(qrow + quad * 4 + r) * NK + s * 64 + 4 * l15));

  for (int t = 0; t < 16; ++t) {
    int buf = t & 1;
    __syncthreads();  // stage(t) + bias(t) landed; buf^1 reads done

    if (t < 15) STAGE(buf ^ 1, (t + 1) * 128)

    // move bias into S accumulators, then start prefetching tile t+1
    f32x4 s2[2][4];
#pragma unroll
    for (int s = 0; s < 2; s++)
#pragma unroll
      for (int jt = 0; jt < 4; jt++)
#pragma unroll
        for (int r = 0; r < 4; r++)
          s2[s][jt][r] = spc[s * 4 + r][jt];

    if (t < 15) {
      const float* bn_ = bh + (size_t)(t + 1) * 128;
#pragma unroll
      for (int s = 0; s < 2; s++)
#pragma unroll
        for (int r = 0; r < 4; r++)
          spc[s * 4 + r] = __builtin_nontemporal_load(
              (const f32x4*)(bn_ + (size_t)(qrow + quad * 4 + r) * NK + s * 64 + 4 * l15));
    }

    const __bf16* Kb = &Kt[buf][0];
    const __bf16* Vb = &Vt[buf][0];

#pragma unroll
    for (int s = 0; s < 2; s++) {
      // K fragments: permuted rows R = s*64 + 4*l15 + jt; f(R)= (R>>2)&7 = l15&7
      bf16x8 b_k[4][2];
#pragma unroll
      for (int jt = 0; jt < 4; jt++)
#pragma unroll
        for (int kk = 0; kk < 2; kk++) {
          int R = s * 64 + 4 * l15 + jt;
          int pc = (quad + 4 * kk) ^ (l15 & 7);
          b_k[jt][kk] = *(const bf16x8*)(Kb + R * 64 + pc * 8);
        }

      __builtin_amdgcn_s_setprio(1);
#pragma unroll
      for (int jt = 0; jt < 4; jt++)
#pragma unroll
        for (int kk = 0; kk < 2; kk++)
          s2[s][jt] = __builtin_amdgcn_mfma_f32_16x16x32_bf16(a_q[kk], b_k[jt][kk], s2[s][jt], 0, 0, 0);
      __builtin_amdgcn_s_setprio(0);

      // exp + P store: per r one ds_write_b64 of 4 bf16 (k = 4*l15 + jt)
#pragma unroll
      for (int r = 0; r < 4; r++) {
        bf16x4 w;
#pragma unroll
        for (int jt = 0; jt < 4; jt++) {
          float pv = __expf(s2[s][jt][r]);
          lpart[r] += pv;
          w[jt] = (__bf16)pv;
        }
        *(bf16x4*)(pl + (quad * 4 + r) * 68 + 4 * l15) = w;
      }

      // A-fragment of P: plain [q][k] read
      bf16x8 a_p[2];
#pragma unroll
      for (int kk = 0; kk < 2; kk++) {
        const __bf16* src = pl + l15 * 68 + quad * 8 + kk * 32;
        bf16x4 lo = *(const bf16x4*)src;
        bf16x4 hi = *(const bf16x4*)(src + 4);
        bf16x8 a;
#pragma unroll
        for (int j = 0; j < 4; j++) { a[j] = lo[j]; a[4 + j] = hi[j]; }
        a_p[kk] = a;
      }

      // V fragments: rows jt*16+l15, chunk (s*8+kk*4+quad) ^ l15
      bf16x8 b_v[4][2];
#pragma unroll
      for (int jt = 0; jt < 4; jt++)
#pragma unroll
        for (int kk = 0; kk < 2; kk++) {
          int R = jt * 16 + l15;
          int pc = (s * 8 + kk * 4 + quad) ^ l15;
          b_v[jt][kk] = *(const bf16x8*)(Vb + R * 128 + pc * 8);
        }

      __builtin_amdgcn_s_setprio(1);
#pragma unroll
      for (int jt = 0; jt < 4; jt++)
#pragma unroll
        for (int kk = 0; kk < 2; kk++)
          acc_o[jt] = __builtin_amdgcn_mfma_f32_16x16x32_bf16(a_p[kk], b_v[jt][kk], acc_o[jt], 0, 0, 0);
      __builtin_amdgcn_s_setprio(0);
    }
  }

  // epilogue: 16-lane row-sum reduce, gate, store
#pragma unroll
  for (int off = 1; off < 16; off <<= 1)
#pragma unroll
    for (int r = 0; r < 4; r++) lpart[r] += __shfl_xor(lpart[r], off);
  float inv[4];
#pragma unroll
  for (int r = 0; r < 4; r++) inv[r] = 1.f / lpart[r];
#pragma unroll
  for (int jt = 0; jt < 4; jt++)
#pragma unroll
    for (int r = 0; r < 4; r++) {
      int q = qrow + quad * 4 + r;
      int d = jt * 16 + l15;
      float g = gate[(size_t)q * HC + h * HD + d];
      out[((size_t)q * NH + h) * HD + d] = acc_o[jt][r] * inv[r] * g;
    }
}

// ---------- launch ----------
extern "C" void kernel_launch(void* const* d_in, const int* in_sizes, int n_in,
                              void* d_out, int out_size, void* d_ws, size_t ws_size,
                              hipStream_t stream) {
  const float* q_data   = (const float*)d_in[0];
  const float* m_data   = (const float*)d_in[1];
  const float* bias     = (const float*)d_in[2];
  const float* query_w  = (const float*)d_in[3];
  const float* query_b  = (const float*)d_in[4];
  const float* key_w    = (const float*)d_in[5];
  const float* value_w  = (const float*)d_in[6];
  const float* gating_w = (const float*)d_in[7];
  float* out = (float*)d_out;

  char* ws = (char*)d_ws;
  __bf16* Aq   = (__bf16*)(ws);
  __bf16* Am   = (__bf16*)(ws + ((size_t)4 << 20));
  __bf16* Wq   = (__bf16*)(ws + ((size_t)8 << 20));
  __bf16* Wk   = (__bf16*)(ws + ((size_t)10 << 20));
  __bf16* Wv   = (__bf16*)(ws + ((size_t)12 << 20));
  __bf16* Wg   = (__bf16*)(ws + ((size_t)14 << 20));
  __bf16* qbuf = (__bf16*)(ws + ((size_t)16 << 20));
  __bf16* kbuf = (__bf16*)(ws + ((size_t)20 << 20));
  __bf16* vtb  = (__bf16*)(ws + ((size_t)24 << 20));
  float*  gbuf = (float*)(ws + ((size_t)28 << 20));

  prep_fused<<<5120, 256, 0, stream>>>(q_data, m_data, Aq, Am,
                                       query_w, key_w, value_w, gating_w,
                                       Wq, Wk, Wv, Wg);
  proj_gemm<<<512, 256, 0, stream>>>(Aq, Am, Wq, Wk, Wv, Wg, query_b, qbuf, kbuf, vtb, gbuf);
  attn<<<512, 256, 0, stream>>>(qbuf, kbuf, vtb, gbuf, bias, out);
}